// Round 2
// baseline (296.742 us; speedup 1.0000x reference)
//
#include <hip/hip_runtime.h>

#define NE 8
#define CAP 1024
#define HD 1024
#define ID 1408
#define TT 2048

typedef __attribute__((ext_vector_type(8))) short bf16x8;
typedef __attribute__((ext_vector_type(4))) float f32x4;
typedef unsigned short u16;
typedef unsigned int u32;
typedef unsigned long long u64;

__device__ __forceinline__ u16 f2bf(float f) {
  u32 u = __float_as_uint(f);
  u = (u + 0x7fffu + ((u >> 16) & 1u)) >> 16;
  return (u16)u;
}

__device__ __forceinline__ bf16x8 pack8(float4 a, float4 b) {
  bf16x8 r;
  r[0] = (short)f2bf(a.x); r[1] = (short)f2bf(a.y);
  r[2] = (short)f2bf(a.z); r[3] = (short)f2bf(a.w);
  r[4] = (short)f2bf(b.x); r[5] = (short)f2bf(b.y);
  r[6] = (short)f2bf(b.z); r[7] = (short)f2bf(b.w);
  return r;
}

__device__ __forceinline__ void async_cp16(const void* g, void* l) {
  __builtin_amdgcn_global_load_lds(
      (const __attribute__((address_space(1))) u32*)g,
      (__attribute__((address_space(3))) u32*)l, 16, 0, 0);
}

// ---------------- fused prep + routing (unchanged from round 1) ----------------
#define W1B (NE * 2 * ID / 4)     // 5632 blocks, 4 rows each
#define W2B (NE * HD * ID / 4096) // 2816 blocks, 1024 float4 each
#define XB (TT * HD / 4096)       // 512 blocks, x cvt + out zero
__global__ __launch_bounds__(256) void prep_kernel(
    const float4* __restrict__ w1, bf16x8* __restrict__ bw1,
    const float4* __restrict__ w2, bf16x8* __restrict__ bw2,
    const float4* __restrict__ x, bf16x8* __restrict__ bx,
    float4* __restrict__ out, const int* __restrict__ ids,
    int* __restrict__ rowmap, int* __restrict__ counts) {
  int b = blockIdx.x;
  int tid = threadIdx.x;
  if (b == 0) {
    __shared__ unsigned char ids_s[TT * 2];
    __shared__ int sc[256][NE + 1];
    for (int i = tid; i < TT * 2; i += 256) ids_s[i] = (unsigned char)ids[i];
    __syncthreads();
    int base = tid * 16;
    u64 own64 = 0;
#pragma unroll
    for (int j = 0; j < 16; ++j) own64 += 1ull << (ids_s[base + j] * 8);
    int own[NE];
#pragma unroll
    for (int e = 0; e < NE; ++e) {
      own[e] = (int)((own64 >> (e * 8)) & 0xff);
      sc[tid][e] = own[e];
    }
    __syncthreads();
    for (int off = 1; off < 256; off <<= 1) {
      int v[NE];
      if (tid >= off) {
#pragma unroll
        for (int e = 0; e < NE; ++e) v[e] = sc[tid - off][e];
      }
      __syncthreads();
      if (tid >= off) {
#pragma unroll
        for (int e = 0; e < NE; ++e) sc[tid][e] += v[e];
      }
      __syncthreads();
    }
    if (tid == 255) {
#pragma unroll
      for (int e = 0; e < NE; ++e) counts[e] = sc[255][e] < CAP ? sc[255][e] : CAP;
    }
    int excl[NE];
#pragma unroll
    for (int e = 0; e < NE; ++e) excl[e] = sc[tid][e] - own[e];
    __syncthreads();
#pragma unroll
    for (int e = 0; e < NE; ++e) sc[tid][e] = excl[e];
#pragma unroll
    for (int j = 0; j < 16; ++j) {
      int f = base + j;
      int e = ids_s[f];
      int p = sc[tid][e]++;
      if (p < CAP) rowmap[e * CAP + p] = f;
    }
    return;
  }
  int bb = b - 1;
  if (bb < W1B) {
    int rl = tid >> 6, c = tid & 63;
    int g = bb * 4 + rl;
    int e = g / (2 * ID);
    int n = g - e * (2 * ID);
    int j = (n < ID) ? n : (n - ID);
    int np = (j >> 4) * 32 + (j & 15) + ((n < ID) ? 0 : 16);
    const float4* src = w1 + ((size_t)e * 2 * ID + n) * (HD / 4);
    bf16x8* dst = bw1 + ((size_t)e * 2 * ID + np) * (HD / 8);
    float4 v0 = src[c * 2];
    float4 v1 = src[c * 2 + 1];
    float4 v2 = src[128 + c * 2];
    float4 v3 = src[128 + c * 2 + 1];
    dst[c] = pack8(v0, v1);
    dst[64 + c] = pack8(v2, v3);
  } else if (bb < W1B + W2B) {
    size_t base4 = (size_t)(bb - W1B) * 1024;
    float4 v0 = w2[base4 + tid * 2];
    float4 v1 = w2[base4 + tid * 2 + 1];
    float4 v2 = w2[base4 + 512 + tid * 2];
    float4 v3 = w2[base4 + 512 + tid * 2 + 1];
    bf16x8* dst = bw2 + base4 / 2;
    dst[tid] = pack8(v0, v1);
    dst[256 + tid] = pack8(v2, v3);
  } else {
    size_t base4 = (size_t)(bb - W1B - W2B) * 1024;
    float4 v0 = x[base4 + tid * 2];
    float4 v1 = x[base4 + tid * 2 + 1];
    float4 v2 = x[base4 + 512 + tid * 2];
    float4 v3 = x[base4 + 512 + tid * 2 + 1];
    bf16x8* dst = bx + base4 / 2;
    dst[tid] = pack8(v0, v1);
    dst[256 + tid] = pack8(v2, v3);
    float4 z = {0.f, 0.f, 0.f, 0.f};
    out[base4 + tid] = z;
    out[base4 + 256 + tid] = z;
    out[base4 + 512 + tid] = z;
    out[base4 + 768 + tid] = z;
  }
}

// ---------------- GEMM1: 128x128, BK=64, PREFETCH double-buffer ----------------
// T3-minimum: STAGE(t+1) issued BEFORE compute(t); one vmcnt(0)+barrier per
// K-step -> load latency hides under ds_read+MFMA. 64KB LDS (2 blocks/CU);
// latency hiding is now intra-block, so low block-residency is OK.
__global__ __launch_bounds__(256) void gemm1_kernel(
    const u16* __restrict__ A, const u16* __restrict__ B, u16* __restrict__ Hb,
    const int* __restrict__ rowmap, const int* __restrict__ counts) {
  int e = blockIdx.x;
  int count = counts[e];
  int n0 = blockIdx.z * 128;
  int tid = threadIdx.x;
  int lane = tid & 63, wid = tid >> 6;
  int wm = wid >> 1, wn = wid & 1;
  int q = lane >> 4, lm = lane & 15;

  __shared__ __align__(16) char sm[2][32768];  // [buf]: A 16KB @0, B 16KB @16K

  int rloc = tid >> 3;
  int chs = ((tid & 7) ^ (rloc & 7)) * 8;
  int ar = (wm * 64 + lm) * 128;
  int br = 16384 + (wn * 64 + lm) * 128;
  int cs0 = (q ^ (lm & 7)) * 16;
  int cs1 = ((4 + q) ^ (lm & 7)) * 16;

  const u16* bP[4];
#pragma unroll
  for (int i = 0; i < 4; ++i)
    bP[i] = B + ((size_t)e * 2 * ID + n0 + rloc + 32 * i) * HD + chs;

  for (int m0 = blockIdx.y * 128; m0 < count; m0 += 512) {
    const u16* aP[4];
#pragma unroll
    for (int i = 0; i < 4; ++i) {
      int gr = m0 + rloc + 32 * i;
      int f = (gr < count) ? rowmap[e * CAP + gr] : 0;
      aP[i] = A + (size_t)(f >> 1) * HD + chs;
    }

    f32x4 zero = {0.f, 0.f, 0.f, 0.f};
    f32x4 acc[4][4];
#pragma unroll
    for (int mi = 0; mi < 4; ++mi)
#pragma unroll
      for (int ni = 0; ni < 4; ++ni) acc[mi][ni] = zero;

#define STAGE1(buf, kt)                                                    \
  do {                                                                     \
    int ko_ = (kt) * 64;                                                   \
    async_cp16(aP[0] + ko_, sm[buf] + (0 * 256 + tid) * 16);               \
    async_cp16(aP[1] + ko_, sm[buf] + (1 * 256 + tid) * 16);               \
    async_cp16(aP[2] + ko_, sm[buf] + (2 * 256 + tid) * 16);               \
    async_cp16(aP[3] + ko_, sm[buf] + (3 * 256 + tid) * 16);               \
    async_cp16(bP[0] + ko_, sm[buf] + 16384 + (0 * 256 + tid) * 16);       \
    async_cp16(bP[1] + ko_, sm[buf] + 16384 + (1 * 256 + tid) * 16);       \
    async_cp16(bP[2] + ko_, sm[buf] + 16384 + (2 * 256 + tid) * 16);       \
    async_cp16(bP[3] + ko_, sm[buf] + 16384 + (3 * 256 + tid) * 16);       \
  } while (0)

    STAGE1(0, 0);
    asm volatile("s_waitcnt vmcnt(0)" ::: "memory");
    __syncthreads();
    int cur = 0;
    for (int kt = 0; kt < HD / 64; ++kt) {
      if (kt < HD / 64 - 1) STAGE1(cur ^ 1, kt + 1);  // prefetch next tile
      const char* sb = sm[cur];
#pragma unroll
      for (int s = 0; s < 2; ++s) {
        int cs = s ? cs1 : cs0;
        bf16x8 af[4], bfr[4];
#pragma unroll
        for (int mi = 0; mi < 4; ++mi)
          af[mi] = *(const bf16x8*)(sb + ar + mi * 2048 + cs);
#pragma unroll
        for (int ni = 0; ni < 4; ++ni)
          bfr[ni] = *(const bf16x8*)(sb + br + ni * 2048 + cs);
        __builtin_amdgcn_s_setprio(1);
#pragma unroll
        for (int mi = 0; mi < 4; ++mi)
#pragma unroll
          for (int ni = 0; ni < 4; ++ni)
            acc[mi][ni] = __builtin_amdgcn_mfma_f32_16x16x32_bf16(af[mi], bfr[ni], acc[mi][ni], 0, 0, 0);
        __builtin_amdgcn_s_setprio(0);
      }
      asm volatile("s_waitcnt vmcnt(0)" ::: "memory");  // next tile landed
      __syncthreads();
      cur ^= 1;
    }

    // ---- fused SiLU epilogue: merged 128x64 u16 tile via LDS repack ----
    u16* smOut = (u16*)sm;  // [128][72] u16 = 18 KB
#pragma unroll
    for (int mi = 0; mi < 4; ++mi) {
#pragma unroll
      for (int k = 0; k < 2; ++k) {
        int colL = wn * 32 + k * 16 + lm;
#pragma unroll
        for (int r = 0; r < 4; ++r) {
          float g = acc[mi][2 * k][r];
          float u = acc[mi][2 * k + 1][r];
          float a = g / (1.f + __expf(-g)) * u;
          int row = wm * 64 + mi * 16 + q * 4 + r;
          smOut[row * 72 + colL] = f2bf(a);
        }
      }
    }
    __syncthreads();
    {
      int row = tid >> 1, seg = tid & 1;
      const u16* sp = smOut + row * 72 + seg * 32;
      bf16x8 v0 = *(const bf16x8*)sp;
      bf16x8 v1 = *(const bf16x8*)(sp + 8);
      bf16x8 v2 = *(const bf16x8*)(sp + 16);
      bf16x8 v3 = *(const bf16x8*)(sp + 24);
      u16* dp = Hb + ((size_t)e * CAP + m0 + row) * ID + (n0 >> 1) + seg * 32;
      *(bf16x8*)dp = v0;
      *(bf16x8*)(dp + 8) = v1;
      *(bf16x8*)(dp + 16) = v2;
      *(bf16x8*)(dp + 24) = v3;
    }
    __syncthreads();  // smOut aliases staging buffers; fence before next m0
  }
}

// ---------------- GEMM2: 128x64, BK=64, PREFETCH dbuf, fused combine ----------
__global__ __launch_bounds__(256) void gemm2_kernel(
    const u16* __restrict__ A, const u16* __restrict__ B, float* __restrict__ out,
    const int* __restrict__ rowmap, const int* __restrict__ counts,
    const float* __restrict__ tw) {
  int e = blockIdx.x;
  int count = counts[e];
  int n0 = blockIdx.z * 64;
  int tid = threadIdx.x;
  int lane = tid & 63, wid = tid >> 6;
  int wm = wid >> 1, wn = wid & 1;
  int q = lane >> 4, lm = lane & 15;

  __shared__ __align__(16) char sm[2][24576];  // [buf]: A 16KB @0, B 8KB @16K

  int rloc = tid >> 3;
  int chs = ((tid & 7) ^ (rloc & 7)) * 8;
  int ar = (wm * 64 + lm) * 128;
  int br = 16384 + (wn * 32 + lm) * 128;
  int cs0 = (q ^ (lm & 7)) * 16;
  int cs1 = ((4 + q) ^ (lm & 7)) * 16;

  const u16* bP[2];
#pragma unroll
  for (int i = 0; i < 2; ++i)
    bP[i] = B + ((size_t)e * HD + n0 + rloc + 32 * i) * ID + chs;

  for (int m0 = blockIdx.y * 128; m0 < count; m0 += 512) {
    const u16* aP[4];
#pragma unroll
    for (int i = 0; i < 4; ++i)
      aP[i] = A + ((size_t)e * CAP + m0 + rloc + 32 * i) * ID + chs;

    f32x4 zero = {0.f, 0.f, 0.f, 0.f};
    f32x4 acc[4][2];
#pragma unroll
    for (int mi = 0; mi < 4; ++mi)
#pragma unroll
      for (int ni = 0; ni < 2; ++ni) acc[mi][ni] = zero;

#define STAGE2(buf, kt)                                                    \
  do {                                                                     \
    int ko_ = (kt) * 64;                                                   \
    async_cp16(aP[0] + ko_, sm[buf] + (0 * 256 + tid) * 16);               \
    async_cp16(aP[1] + ko_, sm[buf] + (1 * 256 + tid) * 16);               \
    async_cp16(aP[2] + ko_, sm[buf] + (2 * 256 + tid) * 16);               \
    async_cp16(aP[3] + ko_, sm[buf] + (3 * 256 + tid) * 16);               \
    async_cp16(bP[0] + ko_, sm[buf] + 16384 + (0 * 256 + tid) * 16);       \
    async_cp16(bP[1] + ko_, sm[buf] + 16384 + (1 * 256 + tid) * 16);       \
  } while (0)

    STAGE2(0, 0);
    asm volatile("s_waitcnt vmcnt(0)" ::: "memory");
    __syncthreads();
    int cur = 0;
    for (int kt = 0; kt < ID / 64; ++kt) {
      if (kt < ID / 64 - 1) STAGE2(cur ^ 1, kt + 1);  // prefetch next tile
      const char* sb = sm[cur];
#pragma unroll
      for (int s = 0; s < 2; ++s) {
        int cs = s ? cs1 : cs0;
        bf16x8 af[4], bfr[2];
#pragma unroll
        for (int mi = 0; mi < 4; ++mi)
          af[mi] = *(const bf16x8*)(sb + ar + mi * 2048 + cs);
#pragma unroll
        for (int ni = 0; ni < 2; ++ni)
          bfr[ni] = *(const bf16x8*)(sb + br + ni * 2048 + cs);
        __builtin_amdgcn_s_setprio(1);
#pragma unroll
        for (int mi = 0; mi < 4; ++mi)
#pragma unroll
          for (int ni = 0; ni < 2; ++ni)
            acc[mi][ni] = __builtin_amdgcn_mfma_f32_16x16x32_bf16(af[mi], bfr[ni], acc[mi][ni], 0, 0, 0);
        __builtin_amdgcn_s_setprio(0);
      }
      asm volatile("s_waitcnt vmcnt(0)" ::: "memory");
      __syncthreads();
      cur ^= 1;
    }

    // fused combine epilogue: out[token, col] += w * y
#pragma unroll
    for (int mi = 0; mi < 4; ++mi) {
#pragma unroll
      for (int r = 0; r < 4; ++r) {
        int grow = m0 + wm * 64 + mi * 16 + q * 4 + r;
        if (grow < count) {
          int f = rowmap[e * CAP + grow];
          float w = tw[f];
          int t = f >> 1;
#pragma unroll
          for (int ni = 0; ni < 2; ++ni) {
            int col = n0 + wn * 32 + ni * 16 + lm;
            atomicAdd(&out[(size_t)t * HD + col], w * acc[mi][ni][r]);
          }
        }
      }
    }
  }
}

extern "C" void kernel_launch(void* const* d_in, const int* in_sizes, int n_in,
                              void* d_out, int out_size, void* d_ws, size_t ws_size,
                              hipStream_t stream) {
  const float* hidden = (const float*)d_in[0];
  const float* w1 = (const float*)d_in[1];
  const float* w2 = (const float*)d_in[2];
  const float* tw = (const float*)d_in[3];
  const int* ids = (const int*)d_in[4];
  float* out = (float*)d_out;

  char* p = (char*)d_ws;
  auto alloc = [&](size_t b) { char* r = p; p += (b + 255) & ~(size_t)255; return r; };
  u16* bw1 = (u16*)alloc((size_t)NE * 2 * ID * HD * 2);   // 46.1 MB (interleaved rows)
  u16* bw2 = (u16*)alloc((size_t)NE * HD * ID * 2);        // 23.1 MB
  u16* bx = (u16*)alloc((size_t)TT * HD * 2);              // 4.2 MB
  u16* hbuf = (u16*)alloc((size_t)NE * CAP * ID * 2);      // 23.1 MB
  int* rowmap = (int*)alloc((size_t)NE * CAP * 4);
  int* counts = (int*)alloc((size_t)NE * 4);

  // single fused launch: route (block 0) | w1 il-cvt | w2 cvt | x cvt + out zero
  prep_kernel<<<1 + W1B + W2B + XB, 256, 0, stream>>>(
      (const float4*)w1, (bf16x8*)bw1, (const float4*)w2, (bf16x8*)bw2,
      (const float4*)hidden, (bf16x8*)bx, (float4*)out, ids, rowmap, counts);

  // GEMM1 + SiLU: hbuf = silu(x.w1g^T) * (x.w1u^T), 128x128 dbuf-prefetch
  gemm1_kernel<<<dim3(NE, 4, 2 * ID / 128), 256, 0, stream>>>(
      bx, bw1, hbuf, rowmap, counts);

  // GEMM2 + combine: out[t,:] += w * (act . w2^T), 128x64 dbuf-prefetch
  gemm2_kernel<<<dim3(NE, 4, HD / 64), 256, 0, stream>>>(
      hbuf, bw2, out, rowmap, counts, tw);
}

// Round 3
// 262.250 us; speedup vs baseline: 1.1315x; 1.1315x over previous
//
#include <hip/hip_runtime.h>

#define NE 8
#define CAP 1024
#define HD 1024
#define ID 1408
#define TT 2048

typedef __attribute__((ext_vector_type(8))) short bf16x8;
typedef __attribute__((ext_vector_type(4))) float f32x4;
typedef unsigned short u16;
typedef unsigned int u32;
typedef unsigned long long u64;

__device__ __forceinline__ u16 f2bf(float f) {
  u32 u = __float_as_uint(f);
  u = (u + 0x7fffu + ((u >> 16) & 1u)) >> 16;
  return (u16)u;
}

__device__ __forceinline__ bf16x8 pack8(float4 a, float4 b) {
  bf16x8 r;
  r[0] = (short)f2bf(a.x); r[1] = (short)f2bf(a.y);
  r[2] = (short)f2bf(a.z); r[3] = (short)f2bf(a.w);
  r[4] = (short)f2bf(b.x); r[5] = (short)f2bf(b.y);
  r[6] = (short)f2bf(b.z); r[7] = (short)f2bf(b.w);
  return r;
}

__device__ __forceinline__ void async_cp16(const void* g, void* l) {
  __builtin_amdgcn_global_load_lds(
      (const __attribute__((address_space(1))) u32*)g,
      (__attribute__((address_space(3))) u32*)l, 16, 0, 0);
}

// ---------------- fused prep + routing (unchanged) ----------------
#define W1B (NE * 2 * ID / 4)     // 5632 blocks, 4 rows each
#define W2B (NE * HD * ID / 4096) // 2816 blocks, 1024 float4 each
#define XB (TT * HD / 4096)       // 512 blocks, x cvt + out zero
__global__ __launch_bounds__(256) void prep_kernel(
    const float4* __restrict__ w1, bf16x8* __restrict__ bw1,
    const float4* __restrict__ w2, bf16x8* __restrict__ bw2,
    const float4* __restrict__ x, bf16x8* __restrict__ bx,
    float4* __restrict__ out, const int* __restrict__ ids,
    int* __restrict__ rowmap, int* __restrict__ counts) {
  int b = blockIdx.x;
  int tid = threadIdx.x;
  if (b == 0) {
    __shared__ unsigned char ids_s[TT * 2];
    __shared__ int sc[256][NE + 1];
    for (int i = tid; i < TT * 2; i += 256) ids_s[i] = (unsigned char)ids[i];
    __syncthreads();
    int base = tid * 16;
    u64 own64 = 0;
#pragma unroll
    for (int j = 0; j < 16; ++j) own64 += 1ull << (ids_s[base + j] * 8);
    int own[NE];
#pragma unroll
    for (int e = 0; e < NE; ++e) {
      own[e] = (int)((own64 >> (e * 8)) & 0xff);
      sc[tid][e] = own[e];
    }
    __syncthreads();
    for (int off = 1; off < 256; off <<= 1) {
      int v[NE];
      if (tid >= off) {
#pragma unroll
        for (int e = 0; e < NE; ++e) v[e] = sc[tid - off][e];
      }
      __syncthreads();
      if (tid >= off) {
#pragma unroll
        for (int e = 0; e < NE; ++e) sc[tid][e] += v[e];
      }
      __syncthreads();
    }
    if (tid == 255) {
#pragma unroll
      for (int e = 0; e < NE; ++e) counts[e] = sc[255][e] < CAP ? sc[255][e] : CAP;
    }
    int excl[NE];
#pragma unroll
    for (int e = 0; e < NE; ++e) excl[e] = sc[tid][e] - own[e];
    __syncthreads();
#pragma unroll
    for (int e = 0; e < NE; ++e) sc[tid][e] = excl[e];
#pragma unroll
    for (int j = 0; j < 16; ++j) {
      int f = base + j;
      int e = ids_s[f];
      int p = sc[tid][e]++;
      if (p < CAP) rowmap[e * CAP + p] = f;
    }
    return;
  }
  int bb = b - 1;
  if (bb < W1B) {
    int rl = tid >> 6, c = tid & 63;
    int g = bb * 4 + rl;
    int e = g / (2 * ID);
    int n = g - e * (2 * ID);
    int j = (n < ID) ? n : (n - ID);
    int np = (j >> 4) * 32 + (j & 15) + ((n < ID) ? 0 : 16);
    const float4* src = w1 + ((size_t)e * 2 * ID + n) * (HD / 4);
    bf16x8* dst = bw1 + ((size_t)e * 2 * ID + np) * (HD / 8);
    float4 v0 = src[c * 2];
    float4 v1 = src[c * 2 + 1];
    float4 v2 = src[128 + c * 2];
    float4 v3 = src[128 + c * 2 + 1];
    dst[c] = pack8(v0, v1);
    dst[64 + c] = pack8(v2, v3);
  } else if (bb < W1B + W2B) {
    size_t base4 = (size_t)(bb - W1B) * 1024;
    float4 v0 = w2[base4 + tid * 2];
    float4 v1 = w2[base4 + tid * 2 + 1];
    float4 v2 = w2[base4 + 512 + tid * 2];
    float4 v3 = w2[base4 + 512 + tid * 2 + 1];
    bf16x8* dst = bw2 + base4 / 2;
    dst[tid] = pack8(v0, v1);
    dst[256 + tid] = pack8(v2, v3);
  } else {
    size_t base4 = (size_t)(bb - W1B - W2B) * 1024;
    float4 v0 = x[base4 + tid * 2];
    float4 v1 = x[base4 + tid * 2 + 1];
    float4 v2 = x[base4 + 512 + tid * 2];
    float4 v3 = x[base4 + 512 + tid * 2 + 1];
    bf16x8* dst = bx + base4 / 2;
    dst[tid] = pack8(v0, v1);
    dst[256 + tid] = pack8(v2, v3);
    float4 z = {0.f, 0.f, 0.f, 0.f};
    out[base4 + tid] = z;
    out[base4 + 256 + tid] = z;
    out[base4 + 512 + tid] = z;
    out[base4 + 768 + tid] = z;
  }
}

// ---------------- GEMM1: 64x128 (r0 geometry), depth-2 counted-vmcnt pipeline -
// 3 LDS buffers x 24KB rotate; stage(t+2) issued in step t; barrier is raw
// s_barrier fused with s_waitcnt vmcnt(6) (NEVER 0 in main loop) so 6 loads
// stay in flight across each barrier (T3/T4). 72KB LDS -> 2 blocks/CU, grid
// 2816 blocks keeps the TLP that r0 proved essential.
#define G1BUF 24576
__global__ __launch_bounds__(256) void gemm1_kernel(
    const u16* __restrict__ A, const u16* __restrict__ B, u16* __restrict__ Hb,
    const int* __restrict__ rowmap, const int* __restrict__ counts) {
  int e = blockIdx.x;
  int count = counts[e];
  int m0 = blockIdx.y * 64;
  if (m0 >= count) return;
  int n0 = blockIdx.z * 128;
  int tid = threadIdx.x;
  int lane = tid & 63, wid = tid >> 6;
  int wm = wid >> 1, wn = wid & 1;
  int q = lane >> 4, lm = lane & 15;

  __shared__ __align__(16) char sm[3 * G1BUF];  // per buf: A 8KB @0, B 16KB @8K

  int rloc = tid >> 3;
  int chs = ((tid & 7) ^ (rloc & 7)) * 8;
  const u16* aP[2];
  const u16* bP[4];
#pragma unroll
  for (int i = 0; i < 2; ++i) {
    int gr = m0 + rloc + 32 * i;
    int f = (gr < count) ? rowmap[e * CAP + gr] : 0;
    aP[i] = A + (size_t)(f >> 1) * HD + chs;
  }
#pragma unroll
  for (int i = 0; i < 4; ++i)
    bP[i] = B + ((size_t)e * 2 * ID + n0 + rloc + 32 * i) * HD + chs;

  f32x4 zero = {0.f, 0.f, 0.f, 0.f};
  f32x4 acc[2][4];
#pragma unroll
  for (int mi = 0; mi < 2; ++mi)
#pragma unroll
    for (int ni = 0; ni < 4; ++ni) acc[mi][ni] = zero;

#define STAGE1(base, kt)                                             \
  do {                                                               \
    int ko_ = (kt) * 64;                                             \
    char* sb_ = (base);                                              \
    async_cp16(aP[0] + ko_, sb_ + (0 * 256 + tid) * 16);             \
    async_cp16(aP[1] + ko_, sb_ + (1 * 256 + tid) * 16);             \
    async_cp16(bP[0] + ko_, sb_ + 8192 + (0 * 256 + tid) * 16);      \
    async_cp16(bP[1] + ko_, sb_ + 8192 + (1 * 256 + tid) * 16);      \
    async_cp16(bP[2] + ko_, sb_ + 8192 + (2 * 256 + tid) * 16);      \
    async_cp16(bP[3] + ko_, sb_ + 8192 + (3 * 256 + tid) * 16);      \
  } while (0)

  STAGE1(sm, 0);
  STAGE1(sm + G1BUF, 1);
  int p = 0, pn2 = 2;
  for (int kt = 0; kt < HD / 64; ++kt) {
    // counted vmcnt: steady-state 12 outstanding (stage t+1 and t+2); wait to
    // 6 -> stage(t) has landed for ALL waves (each wave waited its own), then
    // barrier. Fused in one asm so no ds_read can slip between wait & barrier.
    if (kt == HD / 64 - 1)
      asm volatile("s_waitcnt vmcnt(0)\ns_barrier" ::: "memory");
    else
      asm volatile("s_waitcnt vmcnt(6)\ns_barrier" ::: "memory");
    const char* sb = sm + p * G1BUF;
    if (kt + 2 < HD / 64) STAGE1(sm + pn2 * G1BUF, kt + 2);
#pragma unroll
    for (int s = 0; s < 2; ++s) {
      int cs = ((s * 4 + q) ^ (lm & 7)) * 16;
      bf16x8 af[2], bfr[4];
#pragma unroll
      for (int mi = 0; mi < 2; ++mi)
        af[mi] = *(const bf16x8*)(sb + (wm * 32 + mi * 16 + lm) * 128 + cs);
#pragma unroll
      for (int ni = 0; ni < 4; ++ni)
        bfr[ni] = *(const bf16x8*)(sb + 8192 + (wn * 64 + ni * 16 + lm) * 128 + cs);
      __builtin_amdgcn_s_setprio(1);
#pragma unroll
      for (int mi = 0; mi < 2; ++mi)
#pragma unroll
        for (int ni = 0; ni < 4; ++ni)
          acc[mi][ni] = __builtin_amdgcn_mfma_f32_16x16x32_bf16(af[mi], bfr[ni], acc[mi][ni], 0, 0, 0);
      __builtin_amdgcn_s_setprio(0);
    }
    p = (p == 2) ? 0 : p + 1;
    pn2 = (pn2 == 2) ? 0 : pn2 + 1;
  }
  __syncthreads();  // full drain before LDS reuse by epilogue

  // ---- fused SiLU epilogue (r0-verbatim): merged 64x64 u16 tile ----
  u16* smOut = (u16*)sm;  // [64][72] u16
#pragma unroll
  for (int mi = 0; mi < 2; ++mi) {
#pragma unroll
    for (int k = 0; k < 2; ++k) {
      int colL = wn * 32 + k * 16 + lm;
#pragma unroll
      for (int r = 0; r < 4; ++r) {
        float g = acc[mi][2 * k][r];
        float u = acc[mi][2 * k + 1][r];
        float a = g / (1.f + __expf(-g)) * u;
        int row = wm * 32 + mi * 16 + q * 4 + r;
        smOut[row * 72 + colL] = f2bf(a);
      }
    }
  }
  __syncthreads();
  {
    int row = tid >> 2, seg = tid & 3;
    const u16* sp = smOut + row * 72 + seg * 16;
    bf16x8 v0 = *(const bf16x8*)sp;
    bf16x8 v1 = *(const bf16x8*)(sp + 8);
    u16* dp = Hb + ((size_t)e * CAP + m0 + row) * ID + (n0 >> 1) + seg * 16;
    *(bf16x8*)dp = v0;
    *(bf16x8*)(dp + 8) = v1;
  }
}

// ---------------- GEMM2: 64x64 (r0 geometry), depth-2 counted-vmcnt pipeline --
// 3 x 16KB buffers (48KB -> 3 blocks/CU), vmcnt(4) steady, grid 2048 blocks.
#define G2BUF 16384
__global__ __launch_bounds__(256) void gemm2_kernel(
    const u16* __restrict__ A, const u16* __restrict__ B, float* __restrict__ out,
    const int* __restrict__ rowmap, const int* __restrict__ counts,
    const float* __restrict__ tw) {
  int e = blockIdx.x;
  int count = counts[e];
  int m0 = blockIdx.y * 64;
  if (m0 >= count) return;
  int n0 = blockIdx.z * 64;
  int tid = threadIdx.x;
  int lane = tid & 63, wid = tid >> 6;
  int wm = wid >> 1, wn = wid & 1;
  int q = lane >> 4, lm = lane & 15;

  __shared__ __align__(16) char sm[3 * G2BUF];  // per buf: A 8KB @0, B 8KB @8K

  int rloc = tid >> 3;
  int chs = ((tid & 7) ^ (rloc & 7)) * 8;
  const u16* aP[2];
  const u16* bP[2];
#pragma unroll
  for (int i = 0; i < 2; ++i) {
    aP[i] = A + ((size_t)e * CAP + m0 + rloc + 32 * i) * ID + chs;
    bP[i] = B + ((size_t)e * HD + n0 + rloc + 32 * i) * ID + chs;
  }

  f32x4 zero = {0.f, 0.f, 0.f, 0.f};
  f32x4 acc[2][2];
#pragma unroll
  for (int mi = 0; mi < 2; ++mi)
#pragma unroll
    for (int ni = 0; ni < 2; ++ni) acc[mi][ni] = zero;

#define STAGE2(base, kt)                                             \
  do {                                                               \
    int ko_ = (kt) * 64;                                             \
    char* sb_ = (base);                                              \
    async_cp16(aP[0] + ko_, sb_ + (0 * 256 + tid) * 16);             \
    async_cp16(aP[1] + ko_, sb_ + (1 * 256 + tid) * 16);             \
    async_cp16(bP[0] + ko_, sb_ + 8192 + (0 * 256 + tid) * 16);      \
    async_cp16(bP[1] + ko_, sb_ + 8192 + (1 * 256 + tid) * 16);      \
  } while (0)

  STAGE2(sm, 0);
  STAGE2(sm + G2BUF, 1);
  int p = 0, pn2 = 2;
  for (int kt = 0; kt < ID / 64; ++kt) {
    if (kt == ID / 64 - 1)
      asm volatile("s_waitcnt vmcnt(0)\ns_barrier" ::: "memory");
    else
      asm volatile("s_waitcnt vmcnt(4)\ns_barrier" ::: "memory");
    const char* sb = sm + p * G2BUF;
    if (kt + 2 < ID / 64) STAGE2(sm + pn2 * G2BUF, kt + 2);
#pragma unroll
    for (int s = 0; s < 2; ++s) {
      int cs = ((s * 4 + q) ^ (lm & 7)) * 16;
      bf16x8 af[2], bfr[2];
#pragma unroll
      for (int mi = 0; mi < 2; ++mi)
        af[mi] = *(const bf16x8*)(sb + (wm * 32 + mi * 16 + lm) * 128 + cs);
#pragma unroll
      for (int ni = 0; ni < 2; ++ni)
        bfr[ni] = *(const bf16x8*)(sb + 8192 + (wn * 32 + ni * 16 + lm) * 128 + cs);
      __builtin_amdgcn_s_setprio(1);
#pragma unroll
      for (int mi = 0; mi < 2; ++mi)
#pragma unroll
        for (int ni = 0; ni < 2; ++ni)
          acc[mi][ni] = __builtin_amdgcn_mfma_f32_16x16x32_bf16(af[mi], bfr[ni], acc[mi][ni], 0, 0, 0);
      __builtin_amdgcn_s_setprio(0);
    }
    p = (p == 2) ? 0 : p + 1;
    pn2 = (pn2 == 2) ? 0 : pn2 + 1;
  }

  // fused combine epilogue: out[token, col] += w * y
#pragma unroll
  for (int mi = 0; mi < 2; ++mi) {
#pragma unroll
    for (int r = 0; r < 4; ++r) {
      int grow = m0 + wm * 32 + mi * 16 + q * 4 + r;
      if (grow < count) {
        int f = rowmap[e * CAP + grow];
        float w = tw[f];
        int t = f >> 1;
#pragma unroll
        for (int ni = 0; ni < 2; ++ni) {
          int col = n0 + wn * 32 + ni * 16 + lm;
          atomicAdd(&out[(size_t)t * HD + col], w * acc[mi][ni][r]);
        }
      }
    }
  }
}

extern "C" void kernel_launch(void* const* d_in, const int* in_sizes, int n_in,
                              void* d_out, int out_size, void* d_ws, size_t ws_size,
                              hipStream_t stream) {
  const float* hidden = (const float*)d_in[0];
  const float* w1 = (const float*)d_in[1];
  const float* w2 = (const float*)d_in[2];
  const float* tw = (const float*)d_in[3];
  const int* ids = (const int*)d_in[4];
  float* out = (float*)d_out;

  char* p = (char*)d_ws;
  auto alloc = [&](size_t b) { char* r = p; p += (b + 255) & ~(size_t)255; return r; };
  u16* bw1 = (u16*)alloc((size_t)NE * 2 * ID * HD * 2);   // 46.1 MB (interleaved rows)
  u16* bw2 = (u16*)alloc((size_t)NE * HD * ID * 2);        // 23.1 MB
  u16* bx = (u16*)alloc((size_t)TT * HD * 2);              // 4.2 MB
  u16* hbuf = (u16*)alloc((size_t)NE * CAP * ID * 2);      // 23.1 MB
  int* rowmap = (int*)alloc((size_t)NE * CAP * 4);
  int* counts = (int*)alloc((size_t)NE * 4);

  // single fused launch: route (block 0) | w1 il-cvt | w2 cvt | x cvt + out zero
  prep_kernel<<<1 + W1B + W2B + XB, 256, 0, stream>>>(
      (const float4*)w1, (bf16x8*)bw1, (const float4*)w2, (bf16x8*)bw2,
      (const float4*)hidden, (bf16x8*)bx, (float4*)out, ids, rowmap, counts);

  // GEMM1 + SiLU: 64x128 tiles, counted-vmcnt depth-2 pipeline
  gemm1_kernel<<<dim3(NE, CAP / 64, 2 * ID / 128), 256, 0, stream>>>(
      bx, bw1, hbuf, rowmap, counts);

  // GEMM2 + combine: 64x64 tiles, counted-vmcnt depth-2 pipeline
  gemm2_kernel<<<dim3(NE, CAP / 64, HD / 64), 256, 0, stream>>>(
      hbuf, bw2, out, rowmap, counts, tw);
}